// Round 3
// baseline (407.964 us; speedup 1.0000x reference)
//
#include <hip/hip_runtime.h>

// Problem constants (fixed by setup_inputs):
//   x: (16, 3, 1024, 1024) f32; control_points: (1, 2, 35, 35) f32
//   out = concat(transformed (16,3,1024,1024), deformation_field (2,1024,1024))
#define HW      1024
#define PLANE   (HW * HW)
#define NPLANES 48          // 16 * 3
#define CP      35
#define CPN     (CP * CP)
#define PPT     8           // planes per thread
#define ZCHUNKS (NPLANES / PPT)   // 6

// 8-byte value pair with only 4-byte alignment guarantee (X0 is arbitrary)
struct __attribute__((packed, aligned(4))) f2 { float a, b; };

__global__ __launch_bounds__(256) void bspline_fused_kernel(
    const float* __restrict__ x,
    const float* __restrict__ cp,   // (2, 35, 35)
    float* __restrict__ out)
{
    const int j = blockIdx.x * blockDim.x + threadIdx.x;   // col
    const int i = blockIdx.y;                              // row
    const int pix = i * HW + j;

    // normalized grid coords (linspace(-1,1,1024))
    const float gx = (float)j * (2.0f / 1023.0f) - 1.0f;
    const float gy = (float)i * (2.0f / 1023.0f) - 1.0f;

    // ---- deformation field: bilinear sample of control points ----
    const float cpxc = gx * 17.0f + 17.0f;     // (cpx-1)/2 = 17
    const float cpyc = gy * 17.0f + 17.0f;
    float ix = (cpxc + 1.0f) * 0.5f * 34.0f;   // (W-1) = 34
    float iy = (cpyc + 1.0f) * 0.5f * 34.0f;
    ix = fminf(fmaxf(ix, 0.0f), 34.0f);
    iy = fminf(fmaxf(iy, 0.0f), 34.0f);
    const float ix0f = floorf(ix), iy0f = floorf(iy);
    const float wx = ix - ix0f,    wy = iy - iy0f;
    const int ix0 = (int)ix0f, iy0 = (int)iy0f;
    const int ix1 = min(ix0 + 1, 34), iy1 = min(iy0 + 1, 34);

    const int o00c = iy0 * CP + ix0, o01c = iy0 * CP + ix1;
    const int o10c = iy1 * CP + ix0, o11c = iy1 * CP + ix1;

    float df[2];
    #pragma unroll
    for (int c = 0; c < 2; ++c) {
        const float* cpc = cp + c * CPN;
        const float v00 = cpc[o00c], v01 = cpc[o01c];
        const float v10 = cpc[o10c], v11 = cpc[o11c];
        const float top = v00 * (1.0f - wx) + v01 * wx;
        const float bot = v10 * (1.0f - wx) + v11 * wx;
        df[c] = top * (1.0f - wy) + bot * wy;
    }

    // deformation_field output (after the 48 transformed planes); z==0 only
    if (blockIdx.z == 0) {
        out[NPLANES * PLANE + 0 * PLANE + pix] = df[0];
        out[NPLANES * PLANE + 1 * PLANE + pix] = df[1];
    }

    // ---- image sampling coords (note df channel swap per reference) ----
    const float sxn = gx + df[1];
    const float syn = gy + df[0];
    float fx = (sxn + 1.0f) * 0.5f * 1023.0f;
    float fy = (syn + 1.0f) * 0.5f * 1023.0f;
    fx = fminf(fmaxf(fx, 0.0f), 1023.0f);
    fy = fminf(fmaxf(fy, 0.0f), 1023.0f);

    // Border-equivalent reformulation: clamp base to 1022, weight absorbs edge.
    //   ref: x0=floor(fx), x1=min(x0+1,1023), w=fx-x0
    //   ours: X0=min(floor(fx),1022), ux=fx-X0  (fx=1023 -> ux=1 -> picks v[1023])
    const int X0 = min((int)floorf(fx), HW - 2);
    const int Y0 = min((int)floorf(fy), HW - 2);
    const float ux = fx - (float)X0;
    const float uy = fy - (float)Y0;
    const float omux = 1.0f - ux, omuy = 1.0f - uy;

    const int otop = Y0 * HW + X0;        // adjacent pair (X0, X0+1)
    const int obot = otop + HW;           // row Y0+1

    // ---- 8 planes per thread: 16 independent 8B gathers, ALL in flight ----
    const int p0 = blockIdx.z * PPT;
    const float* __restrict__ xp = x + (size_t)p0 * PLANE;
    float* __restrict__ op = out + (size_t)p0 * PLANE + pix;

    f2 t[PPT], b[PPT];
    #pragma unroll
    for (int p = 0; p < PPT; ++p) {
        const float* bp = xp + (size_t)p * PLANE;
        t[p] = *(const f2*)(bp + otop);
        b[p] = *(const f2*)(bp + obot);
    }
    // Hard scheduling fence: nothing crosses — keeps all 16 loads outstanding
    __builtin_amdgcn_sched_barrier(0);
    #pragma unroll
    for (int p = 0; p < PPT; ++p) {
        const float top = t[p].a * omux + t[p].b * ux;
        const float bot = b[p].a * omux + b[p].b * ux;
        const float r   = top * omuy + bot * uy;
        op[(size_t)p * PLANE] = r;
    }
}

extern "C" void kernel_launch(void* const* d_in, const int* in_sizes, int n_in,
                              void* d_out, int out_size, void* d_ws, size_t ws_size,
                              hipStream_t stream) {
    const float* x  = (const float*)d_in[0];
    const float* cp = (const float*)d_in[1];
    float* out = (float*)d_out;

    dim3 block(256, 1, 1);
    dim3 grid(HW / 256, HW, ZCHUNKS);
    bspline_fused_kernel<<<grid, block, 0, stream>>>(x, cp, out);
}